// Round 9
// baseline (701.365 us; speedup 1.0000x reference)
//
#include <hip/hip_runtime.h>
#include <hip/hip_bf16.h>

typedef __hip_bfloat16 bf16;

#define NT 262144
#define ND 262144
#define EDT 2097152
#define ETT 1048576
#define NSLOT (2*NT)            // [0,NT)=d2t dst slots, [NT,2NT)=tt dst slots
#define NE_TOT (EDT+ETT)        // 3145728
#define NBKT 1024               // coarse buckets, bucket = slot>>9
#define SPB 512                 // slots per bucket
#define BCAP 3072               // per-bucket ebuf capacity (mean ~2048)
#define CH 16384                // edges per phase-1 block
#define NBLK1 (NE_TOT/CH)       // 192

// ---- dual-dtype load/store: isbf==1 -> bf16, else fp32 ----
__device__ __forceinline__ float ldf(const void* p, long i, int isbf){
    if (isbf) return __bfloat162float(((const bf16*)p)[i]);
    return ((const float*)p)[i];
}
__device__ __forceinline__ void stf(void* p, int i, float v, int isbf){
    if (isbf) ((bf16*)p)[i] = __float2bfloat16(v);
    else      ((float*)p)[i] = v;
}
__device__ __forceinline__ float fin(float x){
    return (x==x && x>-3e38f && x<3e38f) ? x : 0.f;
}
// ---- bf16x2 pack/unpack for the gathered xl rows ----
__device__ __forceinline__ unsigned pk2(float a, float b){
    bf16 ha = __float2bfloat16(a), hb = __float2bfloat16(b);
    unsigned short ua = *(unsigned short*)&ha, ub = *(unsigned short*)&hb;
    return ((unsigned)ub<<16) | (unsigned)ua;
}
__device__ __forceinline__ float ulo(unsigned u){ return __uint_as_float(u<<16); }
__device__ __forceinline__ float uhi(unsigned u){ return __uint_as_float(u & 0xffff0000u); }

// ---- input dtype detection: low-16-bit exponent census (see R2 notes) ----
__global__ void detect_kernel(const unsigned* __restrict__ raw, int* __restrict__ flag){
    __shared__ int cnt;
    if (threadIdx.x==0) cnt = 0;
    __syncthreads();
    int c = 0;
    for (int i = threadIdx.x; i < 2048; i += 256){
        unsigned w = raw[i];
        unsigned e = (w >> 7) & 0xFFu;
        if (e >= 116u && e <= 134u) c++;
    }
    atomicAdd(&cnt, c);
    __syncthreads();
    if (threadIdx.x==0) *flag = (cnt > 1024) ? 1 : 0;
}

__global__ void init_cursors_kernel(int* __restrict__ bktCur){
    int i = blockIdx.x*256 + threadIdx.x;
    if (i < NBKT) bktCur[i] = i*BCAP;
}

// ---------------- task stem: x_tasks -> xt[NT,16], fused @tt_Wl -> xl_tt (bf16-packed) ----------------
__global__ __launch_bounds__(256) void stem_task_kernel(
    const void* __restrict__ x, const void* __restrict__ W, const void* __restrict__ bias,
    const void* __restrict__ lng, const void* __restrict__ lnb,
    const void* __restrict__ Wl_tt, float* __restrict__ xt, unsigned* __restrict__ xl_tt,
    const int* __restrict__ flag)
{
    int isbf = *flag;
    __shared__ float sW[192], sb[16], sg[16], sbt[16], sWl[512];
    int t = threadIdx.x;
    if (t < 192) sW[t] = ldf(W, t, isbf);
    if (t < 16){ sb[t]=ldf(bias,t,isbf); sg[t]=ldf(lng,t,isbf); sbt[t]=ldf(lnb,t,isbf); }
    sWl[t]     = ldf(Wl_tt, t,     isbf);
    sWl[t+256] = ldf(Wl_tt, t+256, isbf);
    __syncthreads();
    long i = blockIdx.x*256 + t;
    float f[12];
    #pragma unroll
    for (int k=0;k<12;k++) f[k] = ldf(x, i*12+k, isbf);
    float h[16];
    #pragma unroll
    for (int c=0;c<16;c++){
        float a = sb[c];
        #pragma unroll
        for (int k=0;k<12;k++) a += f[k]*sW[k*16+c];
        h[c]=a;
    }
    float mu=0.f;
    #pragma unroll
    for (int c=0;c<16;c++) mu += h[c];
    mu *= (1.f/16.f);
    float var=0.f;
    #pragma unroll
    for (int c=0;c<16;c++){ float d=h[c]-mu; var += d*d; }
    var *= (1.f/16.f);
    float inv = rsqrtf(var + 1e-5f);
    float v[16];
    #pragma unroll
    for (int c=0;c<16;c++){
        float y = sg[c]*(h[c]-mu)*inv + sbt[c];
        v[c] = fin((y>0.f) ? y : 0.01f*y);
    }
    float4* xp = (float4*)(xt + i*16);
    #pragma unroll
    for (int q=0;q<4;q++) xp[q] = make_float4(v[q*4],v[q*4+1],v[q*4+2],v[q*4+3]);
    float o[32];
    #pragma unroll
    for (int c=0;c<32;c++) o[c]=0.f;
    #pragma unroll
    for (int k=0;k<16;k++){
        float xv=v[k];
        #pragma unroll
        for (int c=0;c<32;c++) o[c] += xv*sWl[k*32+c];
    }
    #pragma unroll
    for (int c=0;c<32;c++) o[c] = fin(o[c]);
    uint4* op = (uint4*)(xl_tt + i*16);
    #pragma unroll
    for (int q=0;q<4;q++)
        op[q] = make_uint4(pk2(o[q*8],o[q*8+1]), pk2(o[q*8+2],o[q*8+3]),
                           pk2(o[q*8+4],o[q*8+5]), pk2(o[q*8+6],o[q*8+7]));
}

// data stem fused with @dt_Wl -> xl_dt (bf16-packed)
__global__ __launch_bounds__(256) void stem_data_transform_kernel(
    const void* __restrict__ x, const void* __restrict__ W, const void* __restrict__ bias,
    const void* __restrict__ lng, const void* __restrict__ lnb,
    const void* __restrict__ Wl, unsigned* __restrict__ xl,
    const int* __restrict__ flag)
{
    int isbf = *flag;
    __shared__ float sW[80], sb[16], sg[16], sbt[16], sWl[512];
    int t = threadIdx.x;
    if (t < 80) sW[t] = ldf(W, t, isbf);
    if (t < 16){ sb[t]=ldf(bias,t,isbf); sg[t]=ldf(lng,t,isbf); sbt[t]=ldf(lnb,t,isbf); }
    sWl[t]     = ldf(Wl, t,     isbf);
    sWl[t+256] = ldf(Wl, t+256, isbf);
    __syncthreads();
    long i = blockIdx.x*256 + t;
    float f[5];
    #pragma unroll
    for (int k=0;k<5;k++) f[k] = ldf(x, i*5+k, isbf);
    float h[16];
    #pragma unroll
    for (int c=0;c<16;c++){
        float a = sb[c];
        #pragma unroll
        for (int k=0;k<5;k++) a += f[k]*sW[k*16+c];
        h[c]=a;
    }
    float mu=0.f;
    #pragma unroll
    for (int c=0;c<16;c++) mu += h[c];
    mu *= (1.f/16.f);
    float var=0.f;
    #pragma unroll
    for (int c=0;c<16;c++){ float d=h[c]-mu; var += d*d; }
    var *= (1.f/16.f);
    float inv = rsqrtf(var + 1e-5f);
    float v[16];
    #pragma unroll
    for (int c=0;c<16;c++){
        float y = sg[c]*(h[c]-mu)*inv + sbt[c];
        v[c] = (y>0.f) ? y : 0.01f*y;
    }
    float o[32];
    #pragma unroll
    for (int c=0;c<32;c++) o[c]=0.f;
    #pragma unroll
    for (int k=0;k<16;k++){
        float xv=v[k];
        #pragma unroll
        for (int c=0;c<32;c++) o[c] += xv*sWl[k*32+c];
    }
    #pragma unroll
    for (int c=0;c<32;c++) o[c] = fin(o[c]);
    uint4* op = (uint4*)(xl + i*16);
    #pragma unroll
    for (int q=0;q<4;q++)
        op[q] = make_uint4(pk2(o[q*8],o[q*8+1]), pk2(o[q*8+2],o[q*8+3]),
                           pk2(o[q*8+4],o[q*8+5]), pk2(o[q*8+6],o[q*8+7]));
}

// ---------------- phase 1: LDS-staged coarse bucket scatter ----------------
// packed edge: src (18 bits) | dloc=slot&511 (10 bits) << 18
__global__ __launch_bounds__(256) void bucket_scatter_kernel(
    const int* __restrict__ ei_dt, const int* __restrict__ mask_dt,
    const int* __restrict__ ei_tt,
    int* __restrict__ bktCur, unsigned* __restrict__ ebuf)
{
    __shared__ int shc[NBKT];
    __shared__ int sloff[NBKT];
    __shared__ int slcur[NBKT];
    __shared__ int spart[256];
    __shared__ unsigned stage[CH];
    int t = threadIdx.x;
    long e0 = (long)blockIdx.x * CH;
    for (int b=t; b<NBKT; b+=256) shc[b]=0;
    __syncthreads();
    for (int i=t; i<CH; i+=256){
        long e = e0 + i;
        int slot, keep;
        if (e < EDT){ keep = mask_dt[e]; slot = ei_dt[EDT+e]; }
        else { long e2 = e-EDT; keep = 1; slot = NT + ei_tt[ETT+e2]; }
        if (keep) atomicAdd(&shc[slot>>9], 1);
    }
    __syncthreads();
    int b4 = t*4;
    int a0=shc[b4], a1=shc[b4+1], a2=shc[b4+2], a3=shc[b4+3];
    int lsum = a0+a1+a2+a3;
    spart[t] = lsum;
    __syncthreads();
    for (int off=1; off<256; off<<=1){
        int x = spart[t];
        int add = (t>=off) ? spart[t-off] : 0;
        __syncthreads();
        spart[t] = x + add;
        __syncthreads();
    }
    int run = spart[t] - lsum;
    int totKept = spart[255];
    sloff[b4]=run;   slcur[b4]=run;   run+=a0;
    sloff[b4+1]=run; slcur[b4+1]=run; run+=a1;
    sloff[b4+2]=run; slcur[b4+2]=run; run+=a2;
    sloff[b4+3]=run; slcur[b4+3]=run;
    if (a0>0) shc[b4]   = atomicAdd(&bktCur[b4],   a0);
    if (a1>0) shc[b4+1] = atomicAdd(&bktCur[b4+1], a1);
    if (a2>0) shc[b4+2] = atomicAdd(&bktCur[b4+2], a2);
    if (a3>0) shc[b4+3] = atomicAdd(&bktCur[b4+3], a3);
    __syncthreads();
    for (int i=t; i<CH; i+=256){
        long e = e0 + i;
        int slot, keep, s;
        if (e < EDT){ keep = mask_dt[e]; s = ei_dt[e]; slot = ei_dt[EDT+e]; }
        else { long e2 = e-EDT; keep = 1; s = ei_tt[e2]; slot = NT + ei_tt[ETT+e2]; }
        if (keep){
            int b = slot>>9;
            int pos = atomicAdd(&slcur[b], 1);
            stage[pos] = (unsigned)s | ((unsigned)(slot & 511) << 18);
        }
    }
    __syncthreads();
    for (int i=t; i<totKept; i+=256){
        int lo=0, hi=NBKT-1;
        while (lo<hi){ int mid=(lo+hi+1)>>1; if (sloff[mid]<=i) lo=mid; else hi=mid-1; }
        ebuf[shc[lo] + (i - sloff[lo])] = stage[i];
    }
}

// ---------------- phase 2: per-bucket LDS CSR + head-split GAT aggregation ----------------
// thread pair (2 lanes) = one dst: lane&1 selects the head. bf16 xl gathers (32B/head).
__global__ __launch_bounds__(256, 3) void bucket_aggregate_kernel(
    const int* __restrict__ bktCur, const unsigned* __restrict__ ebuf,
    const float* __restrict__ xt,
    const unsigned* __restrict__ xl_dt, const unsigned* __restrict__ xl_tt,
    const void* __restrict__ dt_Wr, const void* __restrict__ tt_Wr,
    const void* __restrict__ dt_att, const void* __restrict__ tt_att,
    float* __restrict__ agg, const int* __restrict__ flag)
{
    __shared__ float sWr[512], satt[32];
    __shared__ int scnt[SPB], soff[SPB], scur[SPB], spart[256];
    __shared__ unsigned slist[BCAP];
    int t = threadIdx.x;
    int b = blockIdx.x;
    int which = (b >= NBKT/2);
    int isbf = *flag;
    const void* Wr  = which ? tt_Wr  : dt_Wr;
    const void* att = which ? tt_att : dt_att;
    sWr[t]     = ldf(Wr, t,     isbf);
    sWr[t+256] = ldf(Wr, t+256, isbf);
    if (t < 32) satt[t] = ldf(att, t, isbf);
    scnt[t] = 0; scnt[t+256] = 0;
    __syncthreads();
    int base = b*BCAP;
    int ecnt = bktCur[b] - base;
    if (ecnt > BCAP) ecnt = BCAP;
    if (ecnt < 0) ecnt = 0;
    for (int i=t; i<ecnt; i+=256)
        atomicAdd(&scnt[ebuf[base+i] >> 18], 1);
    __syncthreads();
    int c0 = scnt[2*t], c1 = scnt[2*t+1];
    int ls = c0 + c1;
    spart[t] = ls;
    __syncthreads();
    for (int off=1; off<256; off<<=1){
        int x = spart[t];
        int add = (t>=off) ? spart[t-off] : 0;
        __syncthreads();
        spart[t] = x + add;
        __syncthreads();
    }
    int run = spart[t] - ls;
    soff[2*t] = run; scur[2*t] = run;
    soff[2*t+1] = run + c0; scur[2*t+1] = run + c0;
    __syncthreads();
    for (int i=t; i<ecnt; i+=256){
        unsigned p = ebuf[base+i];
        int pos = atomicAdd(&scur[p >> 18], 1);
        slist[pos] = p & 0x3FFFFu;
    }
    __syncthreads();
    // aggregation: 4 passes x 128 dsts; lane pair = dst, lane&1 = head
    const unsigned* xl = which ? xl_tt : xl_dt;
    int head = t & 1;
    int hb = head*16;
    for (int pass=0; pass<4; pass++){
        int dloc = pass*128 + (t>>1);
        long slot = (long)b*SPB + dloc;
        long d = which ? slot - NT : slot;
        const float4* xp = (const float4*)(xt + d*16);
        float4 x0=xp[0], x1=xp[1], x2=xp[2], x3=xp[3];
        float xtv[16] = {x0.x,x0.y,x0.z,x0.w, x1.x,x1.y,x1.z,x1.w,
                         x2.x,x2.y,x2.z,x2.w, x3.x,x3.y,x3.z,x3.w};
        float xrv[16];
        #pragma unroll
        for (int c=0;c<16;c++) xrv[c]=0.f;
        #pragma unroll
        for (int k=0;k<16;k++){
            float xv=xtv[k];
            #pragma unroll
            for (int c=0;c<16;c++) xrv[c] += xv*sWr[k*32 + hb + c];
        }
        float acc[16];
        #pragma unroll
        for (int c=0;c<16;c++) acc[c]=0.f;
        float den=0.f;
        int e0 = soff[dloc], e1 = scur[dloc];
        for (int e=e0; e<e1; e++){
            long s = slist[e];
            const uint4* p = (const uint4*)(xl + s*16 + head*8);
            uint4 u0 = p[0], u1 = p[1];
            float xs[16] = {ulo(u0.x),uhi(u0.x),ulo(u0.y),uhi(u0.y),
                            ulo(u0.z),uhi(u0.z),ulo(u0.w),uhi(u0.w),
                            ulo(u1.x),uhi(u1.x),ulo(u1.y),uhi(u1.y),
                            ulo(u1.z),uhi(u1.z),ulo(u1.w),uhi(u1.w)};
            float sc=0.f;
            #pragma unroll
            for (int j=0;j<16;j++){
                float m = xs[j] + xrv[j];
                m = m>0.f ? m : 0.2f*m;
                sc += m*satt[hb+j];
            }
            float a = expf(fminf(fin(sc), 60.f));
            den += a;
            #pragma unroll
            for (int c=0;c<16;c++) acc[c] += a*xs[c];
        }
        float inv = 1.f/fmaxf(den, 1e-16f);
        float mean[16];
        #pragma unroll
        for (int c=0;c<16;c++){
            float r = acc[c]*inv;
            mean[c] = fin(0.5f*(r + __shfl_xor(r, 1)));
        }
        float4* op = (float4*)(agg + slot*16);
        if (head==0){
            op[0] = make_float4(mean[0],mean[1],mean[2],mean[3]);
            op[1] = make_float4(mean[4],mean[5],mean[6],mean[7]);
        } else {
            op[2] = make_float4(mean[8],mean[9],mean[10],mean[11]);
            op[3] = make_float4(mean[12],mean[13],mean[14],mean[15]);
        }
    }
}

__device__ __forceinline__ void ln_act16(const float* v, const float* g, const float* b, float* o){
    float mu=0.f;
    #pragma unroll
    for (int c=0;c<16;c++) mu += v[c];
    mu *= (1.f/16.f);
    float var=0.f;
    #pragma unroll
    for (int c=0;c<16;c++){ float d=v[c]-mu; var += d*d; }
    var *= (1.f/16.f);
    float inv = rsqrtf(var + 1e-5f);
    #pragma unroll
    for (int c=0;c<16;c++){
        float y = g[c]*(v[c]-mu)*inv + b[c];
        o[c] = (y>0.f) ? y : 0.01f*y;
    }
}

// ---------------- fuse + pooling (wave-shuffle reduction) ----------------
__global__ __launch_bounds__(256) void fuse_pool_kernel(
    const float* __restrict__ xt,
    const float* __restrict__ agg_dt, const float* __restrict__ agg_tt,
    const void* __restrict__ dt_res, const void* __restrict__ dt_bias,
    const void* __restrict__ tt_res, const void* __restrict__ tt_bias,
    const void* __restrict__ ln1g, const void* __restrict__ ln1b,
    const void* __restrict__ ln2g, const void* __restrict__ ln2b,
    const int* __restrict__ b_tasks, const int* __restrict__ ptrg,
    float* __restrict__ pool_sums, float* __restrict__ pool_cnt,
    void* __restrict__ out, const int* __restrict__ flag)
{
    int isbf = *flag;
    __shared__ float sdt[256], stt[256], sdb[16], stb[16], s1g[16], s1b[16], s2g[16], s2b[16];
    __shared__ float swave[4*48];
    __shared__ int sptr[16];
    __shared__ int s_nonuni;
    int t = threadIdx.x;
    sdt[t] = ldf(dt_res, t, isbf);
    stt[t] = ldf(tt_res, t, isbf);
    if (t < 16){
        sdb[t]=ldf(dt_bias,t,isbf); stb[t]=ldf(tt_bias,t,isbf);
        s1g[t]=ldf(ln1g,t,isbf); s1b[t]=ldf(ln1b,t,isbf);
        s2g[t]=ldf(ln2g,t,isbf); s2b[t]=ldf(ln2b,t,isbf);
        sptr[t]=ptrg[t];
    }
    if (t==0) s_nonuni = 0;
    __syncthreads();
    long i = blockIdx.x*256 + t;
    const float4* xp = (const float4*)(xt + i*16);
    float4 x0=xp[0], x1=xp[1], x2=xp[2], x3=xp[3];
    float vals[48];
    float* xv   = vals;
    float* tupd = vals+16;
    float* dupd = vals+32;
    xv[0]=x0.x; xv[1]=x0.y; xv[2]=x0.z; xv[3]=x0.w;
    xv[4]=x1.x; xv[5]=x1.y; xv[6]=x1.z; xv[7]=x1.w;
    xv[8]=x2.x; xv[9]=x2.y; xv[10]=x2.z; xv[11]=x2.w;
    xv[12]=x3.x; xv[13]=x3.y; xv[14]=x3.z; xv[15]=x3.w;
    {
        const float* ag = agg_dt + i*16;
        float v[16];
        #pragma unroll
        for (int c=0;c<16;c++){
            float r = sdb[c];
            #pragma unroll
            for (int k=0;k<16;k++) r += xv[k]*sdt[k*16+c];
            v[c] = fin(ag[c] + r);
        }
        ln_act16(v, s1g, s1b, dupd);
    }
    {
        const float* ag = agg_tt + i*16;
        float v[16];
        #pragma unroll
        for (int c=0;c<16;c++){
            float r = stb[c];
            #pragma unroll
            for (int k=0;k<16;k++) r += xv[k]*stt[k*16+c];
            v[c] = fin(ag[c] + r);
        }
        ln_act16(v, s2g, s2b, tupd);
    }
    #pragma unroll
    for (int j=0;j<48;j++) vals[j] = fin(vals[j]);
    #pragma unroll
    for (int g=0; g<16; g++){
        if (i == sptr[g]){
            for (int j=0;j<48;j++) stf(out, g*96+j, vals[j], isbf);
        }
    }
    int gi = b_tasks[i];
    int g0 = b_tasks[blockIdx.x*256];
    if (gi != g0) s_nonuni = 1;
    __syncthreads();
    if (s_nonuni){
        for (int j=0;j<48;j++) atomicAdd(&pool_sums[gi*48+j], vals[j]);
        atomicAdd(&pool_cnt[gi], 1.f);
    } else {
        int lane = t & 63, wid = t >> 6;
        #pragma unroll
        for (int j=0;j<48;j++){
            float v = vals[j];
            v += __shfl_down(v, 32);
            v += __shfl_down(v, 16);
            v += __shfl_down(v, 8);
            v += __shfl_down(v, 4);
            v += __shfl_down(v, 2);
            v += __shfl_down(v, 1);
            if (lane==0) swave[wid*48+j] = v;
        }
        __syncthreads();
        if (t < 48){
            float s = swave[t] + swave[48+t] + swave[96+t] + swave[144+t];
            atomicAdd(&pool_sums[g0*48+t], s);
        }
        if (t == 0) atomicAdd(&pool_cnt[g0], 256.f);
    }
}

__global__ void finish_kernel(const float* __restrict__ sums, const float* __restrict__ cnt,
                              void* __restrict__ out, const int* __restrict__ flag)
{
    int t = threadIdx.x;
    if (t >= 768) return;
    int g = t/48, c = t - g*48;
    stf(out, g*96+48+c, fin(sums[g*48+c]/fmaxf(cnt[g],1.f)), *flag);
}

extern "C" void kernel_launch(void* const* d_in, const int* in_sizes, int n_in,
                              void* d_out, int out_size, void* d_ws, size_t ws_size,
                              hipStream_t stream)
{
    const void* x_tasks  = d_in[0];
    const void* x_data   = d_in[1];
    const void* stem_t_W = d_in[2];
    const void* stem_t_b = d_in[3];
    const void* stem_d_W = d_in[4];
    const void* stem_d_b = d_in[5];
    const void* ln_t_g   = d_in[6];
    const void* ln_t_b   = d_in[7];
    const void* ln_d_g   = d_in[8];
    const void* ln_d_b   = d_in[9];
    const void* dt_Wl    = d_in[10];
    const void* dt_Wr    = d_in[11];
    const void* dt_att   = d_in[12];
    const void* dt_res   = d_in[13];
    const void* dt_bias  = d_in[14];
    const void* tt_Wl    = d_in[15];
    const void* tt_Wr    = d_in[16];
    const void* tt_att   = d_in[17];
    const void* tt_res   = d_in[18];
    const void* tt_bias  = d_in[19];
    const void* ln1_g    = d_in[20];
    const void* ln1_b    = d_in[21];
    const void* ln2_g    = d_in[22];
    const void* ln2_b    = d_in[23];
    const int*  ei_dt    = (const int*)d_in[24];
    const int*  mask_dt  = (const int*)d_in[25];
    const int*  ei_tt    = (const int*)d_in[26];
    const int*  b_tasks  = (const int*)d_in[27];
    const int*  ptrg     = (const int*)d_in[28];

    char* w = (char*)d_ws;
    const size_t MB = 1ull<<20;
    float*    xt        = (float*)(w);              // 16 MB  [NT,16] fp32
    unsigned* xl_dt     = (unsigned*)(w + 16*MB);   // 16 MB  [ND,16] bf16x2-packed
    unsigned* xl_tt     = (unsigned*)(w + 32*MB);   // 16 MB  [NT,16] bf16x2-packed
    float*    agg       = (float*)(w + 48*MB);      // 32 MB  [NSLOT,16] fp32
    unsigned* ebuf      = (unsigned*)(w + 80*MB);   // 12 MB (NBKT*BCAP) + slack
    int*      bktCur    = (int*)  (w + 93*MB);      // 4 KB
    float*    pool_sums = (float*)(w + 93*MB + 8192);
    float*    pool_cnt  = (float*)(w + 93*MB + 12288);
    int*      flag      = (int*)  (w + 93*MB + 16384);

    detect_kernel<<<1, 256, 0, stream>>>((const unsigned*)x_tasks, flag);
    init_cursors_kernel<<<(NBKT+255)/256, 256, 0, stream>>>(bktCur);
    hipMemsetAsync(w + 93*MB + 8192, 0, 8192, stream);

    // stems
    stem_task_kernel<<<NT/256, 256, 0, stream>>>(x_tasks, stem_t_W, stem_t_b, ln_t_g, ln_t_b,
                                                 tt_Wl, xt, xl_tt, flag);
    stem_data_transform_kernel<<<ND/256, 256, 0, stream>>>(x_data, stem_d_W, stem_d_b,
                                                           ln_d_g, ln_d_b, dt_Wl, xl_dt, flag);

    // phase 1: coarse bucket scatter (both graphs)
    bucket_scatter_kernel<<<NBLK1, 256, 0, stream>>>(ei_dt, mask_dt, ei_tt, bktCur, ebuf);

    // phase 2: per-bucket LDS CSR + head-split aggregation (both graphs)
    bucket_aggregate_kernel<<<NBKT, 256, 0, stream>>>(bktCur, ebuf, xt, xl_dt, xl_tt,
        dt_Wr, tt_Wr, dt_att, tt_att, agg, flag);

    // fuse + pool + output
    fuse_pool_kernel<<<NT/256, 256, 0, stream>>>(xt, agg, agg + (long)NT*16,
        dt_res, dt_bias, tt_res, tt_bias, ln1_g, ln1_b, ln2_g, ln2_b,
        b_tasks, ptrg, pool_sums, pool_cnt, d_out, flag);
    finish_kernel<<<1, 768, 0, stream>>>(pool_sums, pool_cnt, d_out, flag);
}

// Round 10
// 477.315 us; speedup vs baseline: 1.4694x; 1.4694x over previous
//
#include <hip/hip_runtime.h>
#include <hip/hip_bf16.h>

typedef __hip_bfloat16 bf16;

#define NT 262144
#define ND 262144
#define EDT 2097152
#define ETT 1048576
#define NSLOT (2*NT)            // [0,NT)=d2t dst slots, [NT,2NT)=tt dst slots
#define NE_TOT (EDT+ETT)        // 3145728
#define NBKT 1024               // coarse buckets, bucket = slot>>9
#define SPB 512                 // slots per bucket
#define BCAP 3072               // per-bucket ebuf capacity (mean ~2048)
#define CH 16384                // edges per phase-1 block
#define NBLK1 (NE_TOT/CH)       // 192

// ---- dual-dtype load/store: isbf==1 -> bf16, else fp32 ----
__device__ __forceinline__ float ldf(const void* p, long i, int isbf){
    if (isbf) return __bfloat162float(((const bf16*)p)[i]);
    return ((const float*)p)[i];
}
__device__ __forceinline__ void stf(void* p, int i, float v, int isbf){
    if (isbf) ((bf16*)p)[i] = __float2bfloat16(v);
    else      ((float*)p)[i] = v;
}
__device__ __forceinline__ float fin(float x){
    return (x==x && x>-3e38f && x<3e38f) ? x : 0.f;
}
// ---- bf16x2 pack/unpack for the gathered xl rows ----
__device__ __forceinline__ unsigned pk2(float a, float b){
    bf16 ha = __float2bfloat16(a), hb = __float2bfloat16(b);
    unsigned short ua = *(unsigned short*)&ha, ub = *(unsigned short*)&hb;
    return ((unsigned)ub<<16) | (unsigned)ua;
}
__device__ __forceinline__ float ulo(unsigned u){ return __uint_as_float(u<<16); }
__device__ __forceinline__ float uhi(unsigned u){ return __uint_as_float(u & 0xffff0000u); }

// score contribution of 8 packed channels (leaky_relu(x+xr)·att)
__device__ __forceinline__ float score8(uint4 u, const float* xr, const float* at){
    float s=0.f, m;
    m = ulo(u.x)+xr[0]; m = m>0.f?m:0.2f*m; s += m*at[0];
    m = uhi(u.x)+xr[1]; m = m>0.f?m:0.2f*m; s += m*at[1];
    m = ulo(u.y)+xr[2]; m = m>0.f?m:0.2f*m; s += m*at[2];
    m = uhi(u.y)+xr[3]; m = m>0.f?m:0.2f*m; s += m*at[3];
    m = ulo(u.z)+xr[4]; m = m>0.f?m:0.2f*m; s += m*at[4];
    m = uhi(u.z)+xr[5]; m = m>0.f?m:0.2f*m; s += m*at[5];
    m = ulo(u.w)+xr[6]; m = m>0.f?m:0.2f*m; s += m*at[6];
    m = uhi(u.w)+xr[7]; m = m>0.f?m:0.2f*m; s += m*at[7];
    return s;
}
__device__ __forceinline__ void acc8(uint4 u, float a, float* acc){
    acc[0] += a*ulo(u.x); acc[1] += a*uhi(u.x);
    acc[2] += a*ulo(u.y); acc[3] += a*uhi(u.y);
    acc[4] += a*ulo(u.z); acc[5] += a*uhi(u.z);
    acc[6] += a*ulo(u.w); acc[7] += a*uhi(u.w);
}

// ---- input dtype detection: low-16-bit exponent census (see R2 notes) ----
__global__ void detect_kernel(const unsigned* __restrict__ raw, int* __restrict__ flag){
    __shared__ int cnt;
    if (threadIdx.x==0) cnt = 0;
    __syncthreads();
    int c = 0;
    for (int i = threadIdx.x; i < 2048; i += 256){
        unsigned w = raw[i];
        unsigned e = (w >> 7) & 0xFFu;
        if (e >= 116u && e <= 134u) c++;
    }
    atomicAdd(&cnt, c);
    __syncthreads();
    if (threadIdx.x==0) *flag = (cnt > 1024) ? 1 : 0;
}

__global__ void init_cursors_kernel(int* __restrict__ bktCur){
    int i = blockIdx.x*256 + threadIdx.x;
    if (i < NBKT) bktCur[i] = i*BCAP;
}

// ---------------- task stem: x_tasks -> xt[NT,16], fused @tt_Wl -> xl_tt (bf16-packed) ----------------
__global__ __launch_bounds__(256) void stem_task_kernel(
    const void* __restrict__ x, const void* __restrict__ W, const void* __restrict__ bias,
    const void* __restrict__ lng, const void* __restrict__ lnb,
    const void* __restrict__ Wl_tt, float* __restrict__ xt, unsigned* __restrict__ xl_tt,
    const int* __restrict__ flag)
{
    int isbf = *flag;
    __shared__ float sW[192], sb[16], sg[16], sbt[16], sWl[512];
    int t = threadIdx.x;
    if (t < 192) sW[t] = ldf(W, t, isbf);
    if (t < 16){ sb[t]=ldf(bias,t,isbf); sg[t]=ldf(lng,t,isbf); sbt[t]=ldf(lnb,t,isbf); }
    sWl[t]     = ldf(Wl_tt, t,     isbf);
    sWl[t+256] = ldf(Wl_tt, t+256, isbf);
    __syncthreads();
    long i = blockIdx.x*256 + t;
    float f[12];
    #pragma unroll
    for (int k=0;k<12;k++) f[k] = ldf(x, i*12+k, isbf);
    float h[16];
    #pragma unroll
    for (int c=0;c<16;c++){
        float a = sb[c];
        #pragma unroll
        for (int k=0;k<12;k++) a += f[k]*sW[k*16+c];
        h[c]=a;
    }
    float mu=0.f;
    #pragma unroll
    for (int c=0;c<16;c++) mu += h[c];
    mu *= (1.f/16.f);
    float var=0.f;
    #pragma unroll
    for (int c=0;c<16;c++){ float d=h[c]-mu; var += d*d; }
    var *= (1.f/16.f);
    float inv = rsqrtf(var + 1e-5f);
    float v[16];
    #pragma unroll
    for (int c=0;c<16;c++){
        float y = sg[c]*(h[c]-mu)*inv + sbt[c];
        v[c] = fin((y>0.f) ? y : 0.01f*y);
    }
    float4* xp = (float4*)(xt + i*16);
    #pragma unroll
    for (int q=0;q<4;q++) xp[q] = make_float4(v[q*4],v[q*4+1],v[q*4+2],v[q*4+3]);
    float o[32];
    #pragma unroll
    for (int c=0;c<32;c++) o[c]=0.f;
    #pragma unroll
    for (int k=0;k<16;k++){
        float xv=v[k];
        #pragma unroll
        for (int c=0;c<32;c++) o[c] += xv*sWl[k*32+c];
    }
    #pragma unroll
    for (int c=0;c<32;c++) o[c] = fin(o[c]);
    uint4* op = (uint4*)(xl_tt + i*16);
    #pragma unroll
    for (int q=0;q<4;q++)
        op[q] = make_uint4(pk2(o[q*8],o[q*8+1]), pk2(o[q*8+2],o[q*8+3]),
                           pk2(o[q*8+4],o[q*8+5]), pk2(o[q*8+6],o[q*8+7]));
}

// data stem fused with @dt_Wl -> xl_dt (bf16-packed)
__global__ __launch_bounds__(256) void stem_data_transform_kernel(
    const void* __restrict__ x, const void* __restrict__ W, const void* __restrict__ bias,
    const void* __restrict__ lng, const void* __restrict__ lnb,
    const void* __restrict__ Wl, unsigned* __restrict__ xl,
    const int* __restrict__ flag)
{
    int isbf = *flag;
    __shared__ float sW[80], sb[16], sg[16], sbt[16], sWl[512];
    int t = threadIdx.x;
    if (t < 80) sW[t] = ldf(W, t, isbf);
    if (t < 16){ sb[t]=ldf(bias,t,isbf); sg[t]=ldf(lng,t,isbf); sbt[t]=ldf(lnb,t,isbf); }
    sWl[t]     = ldf(Wl, t,     isbf);
    sWl[t+256] = ldf(Wl, t+256, isbf);
    __syncthreads();
    long i = blockIdx.x*256 + t;
    float f[5];
    #pragma unroll
    for (int k=0;k<5;k++) f[k] = ldf(x, i*5+k, isbf);
    float h[16];
    #pragma unroll
    for (int c=0;c<16;c++){
        float a = sb[c];
        #pragma unroll
        for (int k=0;k<5;k++) a += f[k]*sW[k*16+c];
        h[c]=a;
    }
    float mu=0.f;
    #pragma unroll
    for (int c=0;c<16;c++) mu += h[c];
    mu *= (1.f/16.f);
    float var=0.f;
    #pragma unroll
    for (int c=0;c<16;c++){ float d=h[c]-mu; var += d*d; }
    var *= (1.f/16.f);
    float inv = rsqrtf(var + 1e-5f);
    float v[16];
    #pragma unroll
    for (int c=0;c<16;c++){
        float y = sg[c]*(h[c]-mu)*inv + sbt[c];
        v[c] = (y>0.f) ? y : 0.01f*y;
    }
    float o[32];
    #pragma unroll
    for (int c=0;c<32;c++) o[c]=0.f;
    #pragma unroll
    for (int k=0;k<16;k++){
        float xv=v[k];
        #pragma unroll
        for (int c=0;c<32;c++) o[c] += xv*sWl[k*32+c];
    }
    #pragma unroll
    for (int c=0;c<32;c++) o[c] = fin(o[c]);
    uint4* op = (uint4*)(xl + i*16);
    #pragma unroll
    for (int q=0;q<4;q++)
        op[q] = make_uint4(pk2(o[q*8],o[q*8+1]), pk2(o[q*8+2],o[q*8+3]),
                           pk2(o[q*8+4],o[q*8+5]), pk2(o[q*8+6],o[q*8+7]));
}

// ---------------- phase 1: LDS-staged coarse bucket scatter ----------------
// packed edge: src (18 bits) | dloc=slot&511 (10 bits) << 18
__global__ __launch_bounds__(256) void bucket_scatter_kernel(
    const int* __restrict__ ei_dt, const int* __restrict__ mask_dt,
    const int* __restrict__ ei_tt,
    int* __restrict__ bktCur, unsigned* __restrict__ ebuf)
{
    __shared__ int shc[NBKT];
    __shared__ int sloff[NBKT];
    __shared__ int slcur[NBKT];
    __shared__ int spart[256];
    __shared__ unsigned stage[CH];
    int t = threadIdx.x;
    long e0 = (long)blockIdx.x * CH;
    for (int b=t; b<NBKT; b+=256) shc[b]=0;
    __syncthreads();
    for (int i=t; i<CH; i+=256){
        long e = e0 + i;
        int slot, keep;
        if (e < EDT){ keep = mask_dt[e]; slot = ei_dt[EDT+e]; }
        else { long e2 = e-EDT; keep = 1; slot = NT + ei_tt[ETT+e2]; }
        if (keep) atomicAdd(&shc[slot>>9], 1);
    }
    __syncthreads();
    int b4 = t*4;
    int a0=shc[b4], a1=shc[b4+1], a2=shc[b4+2], a3=shc[b4+3];
    int lsum = a0+a1+a2+a3;
    spart[t] = lsum;
    __syncthreads();
    for (int off=1; off<256; off<<=1){
        int x = spart[t];
        int add = (t>=off) ? spart[t-off] : 0;
        __syncthreads();
        spart[t] = x + add;
        __syncthreads();
    }
    int run = spart[t] - lsum;
    int totKept = spart[255];
    sloff[b4]=run;   slcur[b4]=run;   run+=a0;
    sloff[b4+1]=run; slcur[b4+1]=run; run+=a1;
    sloff[b4+2]=run; slcur[b4+2]=run; run+=a2;
    sloff[b4+3]=run; slcur[b4+3]=run;
    if (a0>0) shc[b4]   = atomicAdd(&bktCur[b4],   a0);
    if (a1>0) shc[b4+1] = atomicAdd(&bktCur[b4+1], a1);
    if (a2>0) shc[b4+2] = atomicAdd(&bktCur[b4+2], a2);
    if (a3>0) shc[b4+3] = atomicAdd(&bktCur[b4+3], a3);
    __syncthreads();
    for (int i=t; i<CH; i+=256){
        long e = e0 + i;
        int slot, keep, s;
        if (e < EDT){ keep = mask_dt[e]; s = ei_dt[e]; slot = ei_dt[EDT+e]; }
        else { long e2 = e-EDT; keep = 1; s = ei_tt[e2]; slot = NT + ei_tt[ETT+e2]; }
        if (keep){
            int b = slot>>9;
            int pos = atomicAdd(&slcur[b], 1);
            stage[pos] = (unsigned)s | ((unsigned)(slot & 511) << 18);
        }
    }
    __syncthreads();
    for (int i=t; i<totKept; i+=256){
        int lo=0, hi=NBKT-1;
        while (lo<hi){ int mid=(lo+hi+1)>>1; if (sloff[mid]<=i) lo=mid; else hi=mid-1; }
        ebuf[shc[lo] + (i - sloff[lo])] = stage[i];
    }
}

// ---------------- phase 2: per-bucket LDS CSR + GAT aggregation ----------------
// R8 structure (1 dst per thread, 2 serial halves); gathers packed bf16 rows
// (one 64B line per edge, kept packed in 16 uints, unpacked on the fly).
__global__ __launch_bounds__(256) void bucket_aggregate_kernel(
    const int* __restrict__ bktCur, const unsigned* __restrict__ ebuf,
    const float* __restrict__ xt,
    const unsigned* __restrict__ xl_dt, const unsigned* __restrict__ xl_tt,
    const void* __restrict__ dt_Wr, const void* __restrict__ tt_Wr,
    const void* __restrict__ dt_att, const void* __restrict__ tt_att,
    float* __restrict__ agg, const int* __restrict__ flag)
{
    __shared__ float sWr[512], satt[32];
    __shared__ int scnt[SPB], soff[SPB], scur[SPB], spart[256];
    __shared__ unsigned slist[BCAP];
    int t = threadIdx.x;
    int b = blockIdx.x;
    int which = (b >= NBKT/2);
    int isbf = *flag;
    const void* Wr  = which ? tt_Wr  : dt_Wr;
    const void* att = which ? tt_att : dt_att;
    sWr[t]     = ldf(Wr, t,     isbf);
    sWr[t+256] = ldf(Wr, t+256, isbf);
    if (t < 32) satt[t] = ldf(att, t, isbf);
    scnt[t] = 0; scnt[t+256] = 0;
    __syncthreads();
    int base = b*BCAP;
    int ecnt = bktCur[b] - base;
    if (ecnt > BCAP) ecnt = BCAP;
    if (ecnt < 0) ecnt = 0;
    for (int i=t; i<ecnt; i+=256)
        atomicAdd(&scnt[ebuf[base+i] >> 18], 1);
    __syncthreads();
    int c0 = scnt[2*t], c1 = scnt[2*t+1];
    int ls = c0 + c1;
    spart[t] = ls;
    __syncthreads();
    for (int off=1; off<256; off<<=1){
        int x = spart[t];
        int add = (t>=off) ? spart[t-off] : 0;
        __syncthreads();
        spart[t] = x + add;
        __syncthreads();
    }
    int run = spart[t] - ls;
    soff[2*t] = run; scur[2*t] = run;
    soff[2*t+1] = run + c0; scur[2*t+1] = run + c0;
    __syncthreads();
    for (int i=t; i<ecnt; i+=256){
        unsigned p = ebuf[base+i];
        int pos = atomicAdd(&scur[p >> 18], 1);
        slist[pos] = p & 0x3FFFFu;
    }
    __syncthreads();
    // aggregate: 2 dsts per thread (serial halves)
    const unsigned* xl = which ? xl_tt : xl_dt;
    for (int half=0; half<2; half++){
        int dloc = t + half*256;
        long slot = (long)b*SPB + dloc;
        long d = which ? slot - NT : slot;
        const float4* xp = (const float4*)(xt + d*16);
        float4 x0=xp[0], x1=xp[1], x2=xp[2], x3=xp[3];
        float xtv[16] = {x0.x,x0.y,x0.z,x0.w, x1.x,x1.y,x1.z,x1.w,
                         x2.x,x2.y,x2.z,x2.w, x3.x,x3.y,x3.z,x3.w};
        float xrv[32];
        #pragma unroll
        for (int c=0;c<32;c++) xrv[c]=0.f;
        #pragma unroll
        for (int k=0;k<16;k++){
            float xv=xtv[k];
            #pragma unroll
            for (int c=0;c<32;c++) xrv[c] += xv*sWr[k*32+c];
        }
        float acc[32];
        #pragma unroll
        for (int c=0;c<32;c++) acc[c]=0.f;
        float den0=0.f, den1=0.f;
        int e0 = soff[dloc], e1 = scur[dloc];
        for (int e=e0; e<e1; e++){
            long s = slist[e];
            const uint4* p = (const uint4*)(xl + s*16);
            uint4 u0 = p[0], u1 = p[1], u2 = p[2], u3 = p[3];
            float sc0 = score8(u0, xrv,    satt)    + score8(u1, xrv+8,  satt+8);
            float sc1 = score8(u2, xrv+16, satt+16) + score8(u3, xrv+24, satt+24);
            float a0 = expf(fminf(fin(sc0), 60.f));
            float a1 = expf(fminf(fin(sc1), 60.f));
            den0 += a0; den1 += a1;
            acc8(u0, a0, acc);    acc8(u1, a0, acc+8);
            acc8(u2, a1, acc+16); acc8(u3, a1, acc+24);
        }
        float id0 = 1.f/fmaxf(den0, 1e-16f);
        float id1 = 1.f/fmaxf(den1, 1e-16f);
        float4* op = (float4*)(agg + slot*16);
        #pragma unroll
        for (int q=0;q<4;q++){
            op[q] = make_float4(
                fin(0.5f*(acc[q*4  ]*id0 + acc[16+q*4  ]*id1)),
                fin(0.5f*(acc[q*4+1]*id0 + acc[16+q*4+1]*id1)),
                fin(0.5f*(acc[q*4+2]*id0 + acc[16+q*4+2]*id1)),
                fin(0.5f*(acc[q*4+3]*id0 + acc[16+q*4+3]*id1)));
        }
    }
}

__device__ __forceinline__ void ln_act16(const float* v, const float* g, const float* b, float* o){
    float mu=0.f;
    #pragma unroll
    for (int c=0;c<16;c++) mu += v[c];
    mu *= (1.f/16.f);
    float var=0.f;
    #pragma unroll
    for (int c=0;c<16;c++){ float d=v[c]-mu; var += d*d; }
    var *= (1.f/16.f);
    float inv = rsqrtf(var + 1e-5f);
    #pragma unroll
    for (int c=0;c<16;c++){
        float y = g[c]*(v[c]-mu)*inv + b[c];
        o[c] = (y>0.f) ? y : 0.01f*y;
    }
}

// ---------------- fuse + pooling (wave-shuffle reduction) ----------------
__global__ __launch_bounds__(256) void fuse_pool_kernel(
    const float* __restrict__ xt,
    const float* __restrict__ agg_dt, const float* __restrict__ agg_tt,
    const void* __restrict__ dt_res, const void* __restrict__ dt_bias,
    const void* __restrict__ tt_res, const void* __restrict__ tt_bias,
    const void* __restrict__ ln1g, const void* __restrict__ ln1b,
    const void* __restrict__ ln2g, const void* __restrict__ ln2b,
    const int* __restrict__ b_tasks, const int* __restrict__ ptrg,
    float* __restrict__ pool_sums, float* __restrict__ pool_cnt,
    void* __restrict__ out, const int* __restrict__ flag)
{
    int isbf = *flag;
    __shared__ float sdt[256], stt[256], sdb[16], stb[16], s1g[16], s1b[16], s2g[16], s2b[16];
    __shared__ float swave[4*48];
    __shared__ int sptr[16];
    __shared__ int s_nonuni;
    int t = threadIdx.x;
    sdt[t] = ldf(dt_res, t, isbf);
    stt[t] = ldf(tt_res, t, isbf);
    if (t < 16){
        sdb[t]=ldf(dt_bias,t,isbf); stb[t]=ldf(tt_bias,t,isbf);
        s1g[t]=ldf(ln1g,t,isbf); s1b[t]=ldf(ln1b,t,isbf);
        s2g[t]=ldf(ln2g,t,isbf); s2b[t]=ldf(ln2b,t,isbf);
        sptr[t]=ptrg[t];
    }
    if (t==0) s_nonuni = 0;
    __syncthreads();
    long i = blockIdx.x*256 + t;
    const float4* xp = (const float4*)(xt + i*16);
    float4 x0=xp[0], x1=xp[1], x2=xp[2], x3=xp[3];
    float vals[48];
    float* xv   = vals;
    float* tupd = vals+16;
    float* dupd = vals+32;
    xv[0]=x0.x; xv[1]=x0.y; xv[2]=x0.z; xv[3]=x0.w;
    xv[4]=x1.x; xv[5]=x1.y; xv[6]=x1.z; xv[7]=x1.w;
    xv[8]=x2.x; xv[9]=x2.y; xv[10]=x2.z; xv[11]=x2.w;
    xv[12]=x3.x; xv[13]=x3.y; xv[14]=x3.z; xv[15]=x3.w;
    {
        const float* ag = agg_dt + i*16;
        float v[16];
        #pragma unroll
        for (int c=0;c<16;c++){
            float r = sdb[c];
            #pragma unroll
            for (int k=0;k<16;k++) r += xv[k]*sdt[k*16+c];
            v[c] = fin(ag[c] + r);
        }
        ln_act16(v, s1g, s1b, dupd);
    }
    {
        const float* ag = agg_tt + i*16;
        float v[16];
        #pragma unroll
        for (int c=0;c<16;c++){
            float r = stb[c];
            #pragma unroll
            for (int k=0;k<16;k++) r += xv[k]*stt[k*16+c];
            v[c] = fin(ag[c] + r);
        }
        ln_act16(v, s2g, s2b, tupd);
    }
    #pragma unroll
    for (int j=0;j<48;j++) vals[j] = fin(vals[j]);
    #pragma unroll
    for (int g=0; g<16; g++){
        if (i == sptr[g]){
            for (int j=0;j<48;j++) stf(out, g*96+j, vals[j], isbf);
        }
    }
    int gi = b_tasks[i];
    int g0 = b_tasks[blockIdx.x*256];
    if (gi != g0) s_nonuni = 1;
    __syncthreads();
    if (s_nonuni){
        for (int j=0;j<48;j++) atomicAdd(&pool_sums[gi*48+j], vals[j]);
        atomicAdd(&pool_cnt[gi], 1.f);
    } else {
        int lane = t & 63, wid = t >> 6;
        #pragma unroll
        for (int j=0;j<48;j++){
            float v = vals[j];
            v += __shfl_down(v, 32);
            v += __shfl_down(v, 16);
            v += __shfl_down(v, 8);
            v += __shfl_down(v, 4);
            v += __shfl_down(v, 2);
            v += __shfl_down(v, 1);
            if (lane==0) swave[wid*48+j] = v;
        }
        __syncthreads();
        if (t < 48){
            float s = swave[t] + swave[48+t] + swave[96+t] + swave[144+t];
            atomicAdd(&pool_sums[g0*48+t], s);
        }
        if (t == 0) atomicAdd(&pool_cnt[g0], 256.f);
    }
}

__global__ void finish_kernel(const float* __restrict__ sums, const float* __restrict__ cnt,
                              void* __restrict__ out, const int* __restrict__ flag)
{
    int t = threadIdx.x;
    if (t >= 768) return;
    int g = t/48, c = t - g*48;
    stf(out, g*96+48+c, fin(sums[g*48+c]/fmaxf(cnt[g],1.f)), *flag);
}

extern "C" void kernel_launch(void* const* d_in, const int* in_sizes, int n_in,
                              void* d_out, int out_size, void* d_ws, size_t ws_size,
                              hipStream_t stream)
{
    const void* x_tasks  = d_in[0];
    const void* x_data   = d_in[1];
    const void* stem_t_W = d_in[2];
    const void* stem_t_b = d_in[3];
    const void* stem_d_W = d_in[4];
    const void* stem_d_b = d_in[5];
    const void* ln_t_g   = d_in[6];
    const void* ln_t_b   = d_in[7];
    const void* ln_d_g   = d_in[8];
    const void* ln_d_b   = d_in[9];
    const void* dt_Wl    = d_in[10];
    const void* dt_Wr    = d_in[11];
    const void* dt_att   = d_in[12];
    const void* dt_res   = d_in[13];
    const void* dt_bias  = d_in[14];
    const void* tt_Wl    = d_in[15];
    const void* tt_Wr    = d_in[16];
    const void* tt_att   = d_in[17];
    const void* tt_res   = d_in[18];
    const void* tt_bias  = d_in[19];
    const void* ln1_g    = d_in[20];
    const void* ln1_b    = d_in[21];
    const void* ln2_g    = d_in[22];
    const void* ln2_b    = d_in[23];
    const int*  ei_dt    = (const int*)d_in[24];
    const int*  mask_dt  = (const int*)d_in[25];
    const int*  ei_tt    = (const int*)d_in[26];
    const int*  b_tasks  = (const int*)d_in[27];
    const int*  ptrg     = (const int*)d_in[28];

    char* w = (char*)d_ws;
    const size_t MB = 1ull<<20;
    float*    xt        = (float*)(w);              // 16 MB  [NT,16] fp32
    unsigned* xl_dt     = (unsigned*)(w + 16*MB);   // 16 MB  [ND,16] bf16x2-packed
    unsigned* xl_tt     = (unsigned*)(w + 32*MB);   // 16 MB  [NT,16] bf16x2-packed
    float*    agg       = (float*)(w + 48*MB);      // 32 MB  [NSLOT,16] fp32
    unsigned* ebuf      = (unsigned*)(w + 80*MB);   // 12 MB (NBKT*BCAP) + slack
    int*      bktCur    = (int*)  (w + 93*MB);      // 4 KB
    float*    pool_sums = (float*)(w + 93*MB + 8192);
    float*    pool_cnt  = (float*)(w + 93*MB + 12288);
    int*      flag      = (int*)  (w + 93*MB + 16384);

    detect_kernel<<<1, 256, 0, stream>>>((const unsigned*)x_tasks, flag);
    init_cursors_kernel<<<(NBKT+255)/256, 256, 0, stream>>>(bktCur);
    hipMemsetAsync(w + 93*MB + 8192, 0, 8192, stream);

    // stems
    stem_task_kernel<<<NT/256, 256, 0, stream>>>(x_tasks, stem_t_W, stem_t_b, ln_t_g, ln_t_b,
                                                 tt_Wl, xt, xl_tt, flag);
    stem_data_transform_kernel<<<ND/256, 256, 0, stream>>>(x_data, stem_d_W, stem_d_b,
                                                           ln_d_g, ln_d_b, dt_Wl, xl_dt, flag);

    // phase 1: coarse bucket scatter (both graphs)
    bucket_scatter_kernel<<<NBLK1, 256, 0, stream>>>(ei_dt, mask_dt, ei_tt, bktCur, ebuf);

    // phase 2: per-bucket LDS CSR + aggregation (both graphs)
    bucket_aggregate_kernel<<<NBKT, 256, 0, stream>>>(bktCur, ebuf, xt, xl_dt, xl_tt,
        dt_Wr, tt_Wr, dt_att, tt_att, agg, flag);

    // fuse + pool + output
    fuse_pool_kernel<<<NT/256, 256, 0, stream>>>(xt, agg, agg + (long)NT*16,
        dt_res, dt_bias, tt_res, tt_bias, ln1_g, ln1_b, ln2_g, ln2_b,
        b_tasks, ptrg, pool_sums, pool_cnt, d_out, flag);
    finish_kernel<<<1, 768, 0, stream>>>(pool_sums, pool_cnt, d_out, flag);
}